// Round 1
// baseline (507.488 us; speedup 1.0000x reference)
//
#include <hip/hip_runtime.h>
#include <stdint.h>

typedef __attribute__((ext_vector_type(8))) short short8;
typedef __attribute__((ext_vector_type(4))) float f32x4;

#define SEQ   2048
#define BSZ   2
#define DIM   1024
#define NHEAD 16
#define HDIM  64
#define MROWS (BSZ*SEQ)   // 4096

__device__ __forceinline__ unsigned short f2bf(float f) {
  unsigned u = __float_as_uint(f);
  unsigned r = u + 0x7fffu + ((u >> 16) & 1u);
  return (unsigned short)(r >> 16);
}
__device__ __forceinline__ unsigned pack2(float a, float b) {
  return (unsigned)f2bf(a) | ((unsigned)f2bf(b) << 16);
}

// ---------------- amax (per-tensor max |x|) ----------------
__global__ __launch_bounds__(256) void amax_kernel(const float* __restrict__ x, int n4,
                                                   unsigned* __restrict__ slot) {
  const float4* x4 = (const float4*)x;
  float m = 0.f;
  for (int i = blockIdx.x * blockDim.x + threadIdx.x; i < n4; i += gridDim.x * blockDim.x) {
    float4 v = x4[i];
    m = fmaxf(m, fmaxf(fmaxf(fabsf(v.x), fabsf(v.y)), fmaxf(fabsf(v.z), fabsf(v.w))));
  }
#pragma unroll
  for (int off = 32; off > 0; off >>= 1) m = fmaxf(m, __shfl_down(m, off));
  if ((threadIdx.x & 63) == 0) atomicMax(slot, __float_as_uint(m));
}

// ------- quantize: integer codes round(x/s), stored exactly as bf16 -------
__global__ __launch_bounds__(256) void quant_kernel(const float* __restrict__ x,
                                                    unsigned short* __restrict__ qc, int n4,
                                                    const unsigned* __restrict__ slot) {
  float amax = __uint_as_float(*slot);
  float s = fmaxf(amax / 127.0f, 1e-8f);
  const float4* x4 = (const float4*)x;
  ushort4* q4 = (ushort4*)qc;
  for (int i = blockIdx.x * blockDim.x + threadIdx.x; i < n4; i += gridDim.x * blockDim.x) {
    float4 v = x4[i];
    ushort4 o;
    o.x = f2bf(rintf(v.x / s));
    o.y = f2bf(rintf(v.y / s));
    o.z = f2bf(rintf(v.z / s));
    o.w = f2bf(rintf(v.w / s));
    q4[i] = o;
  }
}

// ---------------- LoRA first stage: t[row][r] = sum_k x[row,k]*A[r,k] ----------------
template <int NL>
__global__ __launch_bounds__(256) void lora_t_kernel(const float* __restrict__ x,
    const float* __restrict__ A0, const float* __restrict__ A1, const float* __restrict__ A2,
    float* __restrict__ t0, float* __restrict__ t1, float* __restrict__ t2) {
  int row = blockIdx.x;
  const float* xr = x + (size_t)row * DIM;
  float p[NL * 8];
#pragma unroll
  for (int j = 0; j < NL * 8; j++) p[j] = 0.f;
  for (int k = threadIdx.x; k < DIM; k += 256) {
    float xv = xr[k];
#pragma unroll
    for (int r = 0; r < 8; r++) {
      p[r] += xv * A0[r * DIM + k];
      if (NL > 1) p[8 + r] += xv * A1[r * DIM + k];
      if (NL > 2) p[16 + r] += xv * A2[r * DIM + k];
    }
  }
#pragma unroll
  for (int j = 0; j < NL * 8; j++) {
    float v = p[j];
#pragma unroll
    for (int off = 32; off > 0; off >>= 1) v += __shfl_down(v, off);
    p[j] = v;
  }
  __shared__ float red[4][24];
  int wv = threadIdx.x >> 6, lane = threadIdx.x & 63;
  if (lane == 0) {
#pragma unroll
    for (int j = 0; j < NL * 8; j++) red[wv][j] = p[j];
  }
  __syncthreads();
  if ((int)threadIdx.x < NL * 8) {
    int j = threadIdx.x;
    float sv = red[0][j] + red[1][j] + red[2][j] + red[3][j];
    float* tp = (j < 8) ? t0 : ((j < 16) ? t1 : t2);
    tp[(size_t)row * 8 + (j & 7)] = sv;
  }
}

// ---------------- projection GEMM on integer codes (exact) ----------------
// C[i,j] = (sum_k codeX[i,k]*codeW[j,k]) * sx*sw + bias[j] + 2 * sum_r t[i,r]*Bl[j,r]
__global__ __launch_bounds__(256) void proj_kernel(
    const unsigned short* __restrict__ Ac, const unsigned short* __restrict__ Wc,
    const unsigned* __restrict__ sxslot, const unsigned* __restrict__ swslot,
    const float* __restrict__ bias, const float* __restrict__ t,
    const float* __restrict__ Bl, float* __restrict__ Cout) {
  __shared__ alignas(16) unsigned short As[128 * 64];
  __shared__ alignas(16) unsigned short Bs[128 * 64];
  __shared__ float Ts[128 * 8];
  __shared__ float Bls[128 * 8];
  __shared__ float biass[128];

  const int tid = threadIdx.x;
  const int m0 = blockIdx.y * 128, n0 = blockIdx.x * 128;

  for (int i = tid; i < 128 * 8; i += 256) {
    Ts[i] = t[(size_t)m0 * 8 + i];
    Bls[i] = Bl[(size_t)n0 * 8 + i];
  }
  if (tid < 128) biass[tid] = bias[n0 + tid];

  f32x4 acc[4][4];
#pragma unroll
  for (int i = 0; i < 4; i++)
#pragma unroll
    for (int j = 0; j < 4; j++) {
      acc[i][j][0] = 0.f; acc[i][j][1] = 0.f; acc[i][j][2] = 0.f; acc[i][j][3] = 0.f;
    }

  const int wv = tid >> 6, lane = tid & 63;
  const int wr = wv >> 1, wc = wv & 1;
  const int l15 = lane & 15, hi = lane >> 4;

  for (int kt = 0; kt < 16; kt++) {
    const int k0 = kt * 64;
#pragma unroll
    for (int it = 0; it < 4; it++) {
      int idx = it * 256 + tid;
      int r = idx >> 3, c = idx & 7;
      int slot = c ^ (r & 7);
      *(int4*)&As[r * 64 + slot * 8] = *(const int4*)&Ac[(size_t)(m0 + r) * DIM + k0 + c * 8];
      *(int4*)&Bs[r * 64 + slot * 8] = *(const int4*)&Wc[(size_t)(n0 + r) * DIM + k0 + c * 8];
    }
    __syncthreads();
#pragma unroll
    for (int ks = 0; ks < 2; ks++) {
      short8 a[4], b[4];
#pragma unroll
      for (int i = 0; i < 4; i++) {
        int row = wr * 64 + i * 16 + l15;
        int cc = ks * 4 + hi;
        a[i] = *(const short8*)&As[row * 64 + (cc ^ (row & 7)) * 8];
        int col = wc * 64 + i * 16 + l15;
        b[i] = *(const short8*)&Bs[col * 64 + (cc ^ (col & 7)) * 8];
      }
#pragma unroll
      for (int i = 0; i < 4; i++)
#pragma unroll
        for (int j = 0; j < 4; j++)
          acc[i][j] = __builtin_amdgcn_mfma_f32_16x16x32_bf16(a[i], b[j], acc[i][j], 0, 0, 0);
    }
    __syncthreads();
  }

  float sx = fmaxf(__uint_as_float(*sxslot) / 127.0f, 1e-8f);
  float sw = fmaxf(__uint_as_float(*swslot) / 127.0f, 1e-8f);
  float ss = sx * sw;
#pragma unroll
  for (int i = 0; i < 4; i++) {
#pragma unroll
    for (int rr = 0; rr < 4; rr++) {
      int rl = wr * 64 + i * 16 + hi * 4 + rr;
      float tv[8];
#pragma unroll
      for (int q = 0; q < 8; q++) tv[q] = Ts[rl * 8 + q];
#pragma unroll
      for (int j = 0; j < 4; j++) {
        int cl = wc * 64 + j * 16 + l15;
        float lr = 0.f;
#pragma unroll
        for (int q = 0; q < 8; q++) lr += tv[q] * Bls[cl * 8 + q];
        Cout[(size_t)(m0 + rl) * DIM + n0 + cl] = acc[i][j][rr] * ss + biass[cl] + 2.0f * lr;
      }
    }
  }
}

// ---------------- flash attention (bf16 MFMA, f32 online softmax) ----------------
__global__ __launch_bounds__(256) void attn_kernel(
    const float* __restrict__ qbuf, const float* __restrict__ kbuf, const float* __restrict__ vbuf,
    const float* __restrict__ mask, float* __restrict__ obuf) {
  __shared__ alignas(16) unsigned short Qs[64][72];
  __shared__ alignas(16) unsigned short Ks[64][72];
  __shared__ alignas(16) unsigned short Vt[64][72];  // Vt[dim][key]
  __shared__ alignas(16) unsigned short Ps[64][72];
  __shared__ float maskv[64];

  const int tid = threadIdx.x;
  const int q0 = blockIdx.x * 64;
  const int bh = blockIdx.y;
  const int b = bh >> 4, h = bh & 15;
  const size_t rowbase = (size_t)b * SEQ;
  const int wv = tid >> 6, lane = tid & 63, l15 = lane & 15, hi = lane >> 4;

  {  // load Q tile -> bf16 LDS
    int r = tid >> 2, d0 = (tid & 3) * 16;
    const float4* src = (const float4*)(qbuf + (rowbase + q0 + r) * DIM + h * HDIM + d0);
    float4 v0 = src[0], v1 = src[1], v2 = src[2], v3 = src[3];
    int4 w0 = { (int)pack2(v0.x, v0.y), (int)pack2(v0.z, v0.w), (int)pack2(v1.x, v1.y), (int)pack2(v1.z, v1.w) };
    int4 w1 = { (int)pack2(v2.x, v2.y), (int)pack2(v2.z, v2.w), (int)pack2(v3.x, v3.y), (int)pack2(v3.z, v3.w) };
    *(int4*)&Qs[r][d0] = w0;
    *(int4*)&Qs[r][d0 + 8] = w1;
  }

  float mo[4], lsum[4];
  f32x4 o[4];
#pragma unroll
  for (int r = 0; r < 4; r++) { mo[r] = -1e30f; lsum[r] = 0.f; }
#pragma unroll
  for (int d = 0; d < 4; d++) { o[d][0] = 0.f; o[d][1] = 0.f; o[d][2] = 0.f; o[d][3] = 0.f; }

  for (int kt = 0; kt < 32; kt++) {
    const int k0 = kt * 64;
    __syncthreads();
    if (tid < 64) maskv[tid] = (1.0f - mask[rowbase + k0 + tid]) * -10000.0f;
    {
      int r = tid >> 2, d0 = (tid & 3) * 16;
      const float4* ks = (const float4*)(kbuf + (rowbase + k0 + r) * DIM + h * HDIM + d0);
      float4 v0 = ks[0], v1 = ks[1], v2 = ks[2], v3 = ks[3];
      int4 w0 = { (int)pack2(v0.x, v0.y), (int)pack2(v0.z, v0.w), (int)pack2(v1.x, v1.y), (int)pack2(v1.z, v1.w) };
      int4 w1 = { (int)pack2(v2.x, v2.y), (int)pack2(v2.z, v2.w), (int)pack2(v3.x, v3.y), (int)pack2(v3.z, v3.w) };
      *(int4*)&Ks[r][d0] = w0;
      *(int4*)&Ks[r][d0 + 8] = w1;
      const float4* vs = (const float4*)(vbuf + (rowbase + k0 + r) * DIM + h * HDIM + d0);
      float4 u0 = vs[0], u1 = vs[1], u2 = vs[2], u3 = vs[3];
      float vals[16] = { u0.x, u0.y, u0.z, u0.w, u1.x, u1.y, u1.z, u1.w,
                         u2.x, u2.y, u2.z, u2.w, u3.x, u3.y, u3.z, u3.w };
#pragma unroll
      for (int i = 0; i < 16; i++) Vt[d0 + i][r] = f2bf(vals[i]);
    }
    __syncthreads();

    f32x4 s[4];
#pragma unroll
    for (int cb = 0; cb < 4; cb++) { s[cb][0] = 0.f; s[cb][1] = 0.f; s[cb][2] = 0.f; s[cb][3] = 0.f; }
#pragma unroll
    for (int ks = 0; ks < 2; ks++) {
      short8 aq = *(const short8*)&Qs[wv * 16 + l15][ks * 32 + hi * 8];
#pragma unroll
      for (int cb = 0; cb < 4; cb++) {
        short8 bk = *(const short8*)&Ks[cb * 16 + l15][ks * 32 + hi * 8];
        s[cb] = __builtin_amdgcn_mfma_f32_16x16x32_bf16(aq, bk, s[cb], 0, 0, 0);
      }
    }
#pragma unroll
    for (int cb = 0; cb < 4; cb++) {
      float mk = maskv[cb * 16 + l15];
#pragma unroll
      for (int r = 0; r < 4; r++) s[cb][r] = s[cb][r] * 0.125f + mk;
    }
    float al[4];
#pragma unroll
    for (int r = 0; r < 4; r++) {
      float tm = fmaxf(fmaxf(s[0][r], s[1][r]), fmaxf(s[2][r], s[3][r]));
#pragma unroll
      for (int mm = 1; mm < 16; mm <<= 1) tm = fmaxf(tm, __shfl_xor(tm, mm));
      float mn = fmaxf(mo[r], tm);
      al[r] = __expf(mo[r] - mn);
      mo[r] = mn;
    }
    float p[4][4];
    float rs[4] = { 0.f, 0.f, 0.f, 0.f };
#pragma unroll
    for (int cb = 0; cb < 4; cb++)
#pragma unroll
      for (int r = 0; r < 4; r++) {
        float pv = __expf(s[cb][r] - mo[r]);
        p[cb][r] = pv;
        rs[r] += pv;
      }
#pragma unroll
    for (int r = 0; r < 4; r++) {
      float v = rs[r];
#pragma unroll
      for (int mm = 1; mm < 16; mm <<= 1) v += __shfl_xor(v, mm);
      lsum[r] = lsum[r] * al[r] + v;
#pragma unroll
      for (int d = 0; d < 4; d++) o[d][r] *= al[r];
    }
#pragma unroll
    for (int cb = 0; cb < 4; cb++)
#pragma unroll
      for (int r = 0; r < 4; r++)
        Ps[wv * 16 + hi * 4 + r][cb * 16 + l15] = f2bf(p[cb][r]);
#pragma unroll
    for (int ks = 0; ks < 2; ks++) {
      short8 pa = *(const short8*)&Ps[wv * 16 + l15][ks * 32 + hi * 8];
#pragma unroll
      for (int d = 0; d < 4; d++) {
        short8 vvv = *(const short8*)&Vt[d * 16 + l15][ks * 32 + hi * 8];
        o[d] = __builtin_amdgcn_mfma_f32_16x16x32_bf16(pa, vvv, o[d], 0, 0, 0);
      }
    }
  }

#pragma unroll
  for (int r = 0; r < 4; r++) {
    float inv = 1.0f / lsum[r];
    size_t row = rowbase + q0 + wv * 16 + hi * 4 + r;
#pragma unroll
    for (int d = 0; d < 4; d++)
      obuf[row * DIM + h * HDIM + d * 16 + l15] = o[d][r] * inv;
  }
}

// ---------------- launcher ----------------
extern "C" void kernel_launch(void* const* d_in, const int* in_sizes, int n_in,
                              void* d_out, int out_size, void* d_ws, size_t ws_size,
                              hipStream_t stream) {
  const float* x     = (const float*)d_in[0];
  const float* mask  = (const float*)d_in[1];
  const float* q_W   = (const float*)d_in[2];
  const float* q_b   = (const float*)d_in[3];
  const float* q_A   = (const float*)d_in[4];
  const float* q_B   = (const float*)d_in[5];
  const float* k_W   = (const float*)d_in[6];
  const float* k_b   = (const float*)d_in[7];
  const float* k_A   = (const float*)d_in[8];
  const float* k_B   = (const float*)d_in[9];
  const float* v_W   = (const float*)d_in[10];
  const float* v_b   = (const float*)d_in[11];
  const float* v_A   = (const float*)d_in[12];
  const float* v_B   = (const float*)d_in[13];
  const float* o_W   = (const float*)d_in[14];
  const float* o_b   = (const float*)d_in[15];
  const float* o_A   = (const float*)d_in[16];
  const float* o_B   = (const float*)d_in[17];
  float* out = (float*)d_out;

  char* ws = (char*)d_ws;
  const size_t MB = 1u << 20;
  unsigned* slots = (unsigned*)ws;                    // 6 amax slots
  float* t_q = (float*)(ws + 4096);                   // 4096x8 f32 each
  float* t_k = t_q + MROWS * 8;
  float* t_v = t_k + MROWS * 8;
  float* t_o = t_v + MROWS * 8;
  unsigned short* xc  = (unsigned short*)(ws + 1 * MB);   // 4096x1024 bf16 codes
  unsigned short* qWc = (unsigned short*)(ws + 9 * MB);
  unsigned short* kWc = (unsigned short*)(ws + 11 * MB);
  unsigned short* vWc = (unsigned short*)(ws + 13 * MB);
  unsigned short* oWc = (unsigned short*)(ws + 15 * MB);
  float* qbuf = (float*)(ws + 17 * MB);
  float* kbuf = (float*)(ws + 33 * MB);
  float* vbuf = (float*)(ws + 49 * MB);
  float* abuf = (float*)(ws + 65 * MB);
  unsigned short* ac = (unsigned short*)(ws + 81 * MB);

  hipMemsetAsync(ws, 0, 64, stream);

  const int NX4 = (MROWS * DIM) / 4;     // 1048576
  const int NW4 = (DIM * DIM) / 4;       // 262144

  amax_kernel<<<1024, 256, 0, stream>>>(x, NX4, slots + 0);
  amax_kernel<<<256, 256, 0, stream>>>(q_W, NW4, slots + 1);
  amax_kernel<<<256, 256, 0, stream>>>(k_W, NW4, slots + 2);
  amax_kernel<<<256, 256, 0, stream>>>(v_W, NW4, slots + 3);
  amax_kernel<<<256, 256, 0, stream>>>(o_W, NW4, slots + 4);

  quant_kernel<<<1024, 256, 0, stream>>>(x, xc, NX4, slots + 0);
  quant_kernel<<<256, 256, 0, stream>>>(q_W, qWc, NW4, slots + 1);
  quant_kernel<<<256, 256, 0, stream>>>(k_W, kWc, NW4, slots + 2);
  quant_kernel<<<256, 256, 0, stream>>>(v_W, vWc, NW4, slots + 3);
  quant_kernel<<<256, 256, 0, stream>>>(o_W, oWc, NW4, slots + 4);

  lora_t_kernel<3><<<MROWS, 256, 0, stream>>>(x, q_A, k_A, v_A, t_q, t_k, t_v);

  dim3 pg(DIM / 128, MROWS / 128);  // (8, 32)
  proj_kernel<<<pg, 256, 0, stream>>>(xc, qWc, slots + 0, slots + 1, q_b, t_q, q_B, qbuf);
  proj_kernel<<<pg, 256, 0, stream>>>(xc, kWc, slots + 0, slots + 2, k_b, t_k, k_B, kbuf);
  proj_kernel<<<pg, 256, 0, stream>>>(xc, vWc, slots + 0, slots + 3, v_b, t_v, v_B, vbuf);

  attn_kernel<<<dim3(SEQ / 64, BSZ * NHEAD), 256, 0, stream>>>(qbuf, kbuf, vbuf, mask, abuf);

  amax_kernel<<<1024, 256, 0, stream>>>(abuf, NX4, slots + 5);
  quant_kernel<<<1024, 256, 0, stream>>>(abuf, ac, NX4, slots + 5);
  lora_t_kernel<1><<<MROWS, 256, 0, stream>>>(abuf, o_A, nullptr, nullptr, t_o, nullptr, nullptr);
  proj_kernel<<<pg, 256, 0, stream>>>(ac, oWc, slots + 5, slots + 4, o_b, t_o, o_B, out);
}

// Round 2
// 373.462 us; speedup vs baseline: 1.3589x; 1.3589x over previous
//
#include <hip/hip_runtime.h>
#include <stdint.h>

typedef __attribute__((ext_vector_type(8))) short short8;
typedef __attribute__((ext_vector_type(4))) float f32x4;
typedef unsigned short ushort_t;

#define SEQ   2048
#define BSZ   2
#define DIM   1024
#define NHEAD 16
#define HDIM  64
#define MROWS (BSZ*SEQ)   // 4096

__device__ __forceinline__ ushort_t f2bf(float f) {
  unsigned u = __float_as_uint(f);
  unsigned r = u + 0x7fffu + ((u >> 16) & 1u);
  return (ushort_t)(r >> 16);
}

// ---------------- amax ----------------
__global__ __launch_bounds__(256) void amax_kernel(const float* __restrict__ x, int n4,
                                                   unsigned* __restrict__ slot) {
  const float4* x4 = (const float4*)x;
  float m = 0.f;
  for (int i = blockIdx.x * blockDim.x + threadIdx.x; i < n4; i += gridDim.x * blockDim.x) {
    float4 v = x4[i];
    m = fmaxf(m, fmaxf(fmaxf(fabsf(v.x), fabsf(v.y)), fmaxf(fabsf(v.z), fabsf(v.w))));
  }
#pragma unroll
  for (int off = 32; off > 0; off >>= 1) m = fmaxf(m, __shfl_down(m, off));
  if ((threadIdx.x & 63) == 0) atomicMax(slot, __float_as_uint(m));
}

__global__ __launch_bounds__(256) void amax4_kernel(const float* w0, const float* w1,
                                                    const float* w2, const float* w3,
                                                    int n4, unsigned* __restrict__ slots) {
  int y = blockIdx.y;
  const float* x = (y == 0) ? w0 : (y == 1) ? w1 : (y == 2) ? w2 : w3;
  const float4* x4 = (const float4*)x;
  float m = 0.f;
  for (int i = blockIdx.x * blockDim.x + threadIdx.x; i < n4; i += gridDim.x * blockDim.x) {
    float4 v = x4[i];
    m = fmaxf(m, fmaxf(fmaxf(fabsf(v.x), fabsf(v.y)), fmaxf(fabsf(v.z), fabsf(v.w))));
  }
#pragma unroll
  for (int off = 32; off > 0; off >>= 1) m = fmaxf(m, __shfl_down(m, off));
  if ((threadIdx.x & 63) == 0) atomicMax(slots + y, __float_as_uint(m));
}

// ------- quantize: integer codes round(x/s), stored exactly as bf16 -------
__device__ __forceinline__ void quant_body(const float* __restrict__ x,
                                           ushort_t* __restrict__ qc, int n4,
                                           const unsigned* __restrict__ slot,
                                           int gx, int gd) {
  float amax = __uint_as_float(*slot);
  float s = fmaxf(amax / 127.0f, 1e-8f);
  float inv = 1.0f / s;
  const float4* x4 = (const float4*)x;
  ushort4* q4 = (ushort4*)qc;
  for (int i = gx; i < n4; i += gd) {
    float4 v = x4[i];
    ushort4 o;
    o.x = f2bf(rintf(v.x * inv));
    o.y = f2bf(rintf(v.y * inv));
    o.z = f2bf(rintf(v.z * inv));
    o.w = f2bf(rintf(v.w * inv));
    q4[i] = o;
  }
}

__global__ __launch_bounds__(256) void quant_kernel(const float* __restrict__ x,
                                                    ushort_t* __restrict__ qc, int n4,
                                                    const unsigned* __restrict__ slot) {
  quant_body(x, qc, n4, slot, blockIdx.x * blockDim.x + threadIdx.x, gridDim.x * blockDim.x);
}

__global__ __launch_bounds__(256) void quant4_kernel(const float* w0, const float* w1,
                                                     const float* w2, const float* w3,
                                                     ushort_t* q0, ushort_t* q1,
                                                     ushort_t* q2, ushort_t* q3,
                                                     int n4, const unsigned* __restrict__ slots) {
  int y = blockIdx.y;
  const float* x = (y == 0) ? w0 : (y == 1) ? w1 : (y == 2) ? w2 : w3;
  ushort_t* q = (y == 0) ? q0 : (y == 1) ? q1 : (y == 2) ? q2 : q3;
  quant_body(x, q, n4, slots + y, blockIdx.x * blockDim.x + threadIdx.x, gridDim.x * blockDim.x);
}

// ---------------- LoRA first stage: t[row][r] = sum_k x[row,k]*A[r,k] ----------------
template <int NL>
__global__ __launch_bounds__(256) void lora_t_kernel(const float* __restrict__ x,
    const float* __restrict__ A0, const float* __restrict__ A1, const float* __restrict__ A2,
    float* __restrict__ t0, float* __restrict__ t1, float* __restrict__ t2) {
  int row = blockIdx.x;
  const float* xr = x + (size_t)row * DIM;
  float p[NL * 8];
#pragma unroll
  for (int j = 0; j < NL * 8; j++) p[j] = 0.f;
  for (int k = threadIdx.x; k < DIM; k += 256) {
    float xv = xr[k];
#pragma unroll
    for (int r = 0; r < 8; r++) {
      p[r] += xv * A0[r * DIM + k];
      if (NL > 1) p[8 + r] += xv * A1[r * DIM + k];
      if (NL > 2) p[16 + r] += xv * A2[r * DIM + k];
    }
  }
#pragma unroll
  for (int j = 0; j < NL * 8; j++) {
    float v = p[j];
#pragma unroll
    for (int off = 32; off > 0; off >>= 1) v += __shfl_down(v, off);
    p[j] = v;
  }
  __shared__ float red[4][24];
  int wv = threadIdx.x >> 6, lane = threadIdx.x & 63;
  if (lane == 0) {
#pragma unroll
    for (int j = 0; j < NL * 8; j++) red[wv][j] = p[j];
  }
  __syncthreads();
  if ((int)threadIdx.x < NL * 8) {
    int j = threadIdx.x;
    float sv = red[0][j] + red[1][j] + red[2][j] + red[3][j];
    float* tp = (j < 8) ? t0 : ((j < 16) ? t1 : t2);
    tp[(size_t)row * 8 + (j & 7)] = sv;
  }
}

// ---------------- projection GEMM on integer codes (exact) ----------------
// tile: 128 rows (M) x BN cols; 4 waves in 2x2; BN in {128, 64}
template <bool BF16OUT, int BN>
__device__ __forceinline__ void proj_body(
    const ushort_t* __restrict__ Ac, const ushort_t* __restrict__ Wc,
    const unsigned* __restrict__ sxslot, const unsigned* __restrict__ swslot,
    const float* __restrict__ bias, const float* __restrict__ t,
    const float* __restrict__ Bl, void* __restrict__ Cout,
    int m0, int n0) {
  __shared__ alignas(16) ushort_t As[128 * 64];
  __shared__ alignas(16) ushort_t Bs[BN * 64];
  __shared__ float Ts[128 * 8];
  __shared__ float Bls[BN * 8];
  __shared__ float biass[BN];

  const int tid = threadIdx.x;
  constexpr int NJ = BN / 32;          // col 16-blocks per wave
  constexpr int BITS = BN * 8 / 256;   // B staging iters

  for (int i = tid; i < 128 * 8; i += 256) Ts[i] = t[(size_t)m0 * 8 + i];
  for (int i = tid; i < BN * 8; i += 256) Bls[i] = Bl[(size_t)n0 * 8 + i];
  if (tid < BN) biass[tid] = bias[n0 + tid];

  f32x4 acc[4][NJ];
#pragma unroll
  for (int i = 0; i < 4; i++)
#pragma unroll
    for (int j = 0; j < NJ; j++) {
      acc[i][j][0] = 0.f; acc[i][j][1] = 0.f; acc[i][j][2] = 0.f; acc[i][j][3] = 0.f;
    }

  const int wv = tid >> 6, lane = tid & 63;
  const int wr = wv >> 1, wc = wv & 1;
  const int l15 = lane & 15, hi = lane >> 4;

  for (int kt = 0; kt < 16; kt++) {
    const int k0 = kt * 64;
#pragma unroll
    for (int it = 0; it < 4; it++) {
      int idx = it * 256 + tid;
      int r = idx >> 3, c = idx & 7;
      *(int4*)&As[r * 64 + (c ^ (r & 7)) * 8] = *(const int4*)&Ac[(size_t)(m0 + r) * DIM + k0 + c * 8];
    }
#pragma unroll
    for (int it = 0; it < BITS; it++) {
      int idx = it * 256 + tid;
      int r = idx >> 3, c = idx & 7;
      *(int4*)&Bs[r * 64 + (c ^ (r & 7)) * 8] = *(const int4*)&Wc[(size_t)(n0 + r) * DIM + k0 + c * 8];
    }
    __syncthreads();
#pragma unroll
    for (int ks = 0; ks < 2; ks++) {
      short8 a[4], b[NJ];
#pragma unroll
      for (int i = 0; i < 4; i++) {
        int row = wr * 64 + i * 16 + l15;
        a[i] = *(const short8*)&As[row * 64 + ((ks * 4 + hi) ^ (row & 7)) * 8];
      }
#pragma unroll
      for (int j = 0; j < NJ; j++) {
        int col = wc * (BN / 2) + j * 16 + l15;
        b[j] = *(const short8*)&Bs[col * 64 + ((ks * 4 + hi) ^ (col & 7)) * 8];
      }
#pragma unroll
      for (int i = 0; i < 4; i++)
#pragma unroll
        for (int j = 0; j < NJ; j++)
          acc[i][j] = __builtin_amdgcn_mfma_f32_16x16x32_bf16(a[i], b[j], acc[i][j], 0, 0, 0);
    }
    __syncthreads();
  }

  float sx = fmaxf(__uint_as_float(*sxslot) / 127.0f, 1e-8f);
  float sw = fmaxf(__uint_as_float(*swslot) / 127.0f, 1e-8f);
  float ss = sx * sw;
#pragma unroll
  for (int i = 0; i < 4; i++) {
#pragma unroll
    for (int rr = 0; rr < 4; rr++) {
      int rl = wr * 64 + i * 16 + hi * 4 + rr;
      float tv[8];
#pragma unroll
      for (int q = 0; q < 8; q++) tv[q] = Ts[rl * 8 + q];
#pragma unroll
      for (int j = 0; j < NJ; j++) {
        int cl = wc * (BN / 2) + j * 16 + l15;
        float lr = 0.f;
#pragma unroll
        for (int q = 0; q < 8; q++) lr += tv[q] * Bls[cl * 8 + q];
        float val = acc[i][j][rr] * ss + biass[cl] + 2.0f * lr;
        if (BF16OUT)
          ((ushort_t*)Cout)[(size_t)(m0 + rl) * DIM + n0 + cl] = f2bf(val);
        else
          ((float*)Cout)[(size_t)(m0 + rl) * DIM + n0 + cl] = val;
      }
    }
  }
}

struct ProjSet {
  const ushort_t* W; const unsigned* sw; const float* bias;
  const float* t; const float* Bl; ushort_t* out;
};

__global__ __launch_bounds__(256) void proj_qkv_kernel(
    const ushort_t* __restrict__ Ac, const unsigned* __restrict__ sxslot,
    ProjSet pq, ProjSet pk, ProjSet pv) {
  ProjSet P = (blockIdx.z == 0) ? pq : (blockIdx.z == 1) ? pk : pv;
  proj_body<true, 128>(Ac, P.W, sxslot, P.sw, P.bias, P.t, P.Bl, P.out,
                       blockIdx.y * 128, blockIdx.x * 128);
}

__global__ __launch_bounds__(256) void proj_out_kernel(
    const ushort_t* __restrict__ Ac, const ushort_t* __restrict__ Wc,
    const unsigned* __restrict__ sxslot, const unsigned* __restrict__ swslot,
    const float* __restrict__ bias, const float* __restrict__ t,
    const float* __restrict__ Bl, float* __restrict__ Cout) {
  proj_body<false, 64>(Ac, Wc, sxslot, swslot, bias, t, Bl, Cout,
                       blockIdx.y * 128, blockIdx.x * 64);
}

// ---------------- V transpose: vb[token][1024] bf16 -> vT[bh*64+d][2048] bf16 ----------------
__global__ __launch_bounds__(64) void vtrans_kernel(const ushort_t* __restrict__ vb,
                                                    ushort_t* __restrict__ vT) {
  const int s0 = blockIdx.x * 64;
  const int bh = blockIdx.y;
  const int b = bh >> 4, h = bh & 15;
  const int t = threadIdx.x;
  const int dd = t >> 3, sd = t & 7;   // 8x8 subtile grid

  union U { int4 v; ushort_t u[8]; };
  U in[8], out[8];
#pragma unroll
  for (int j = 0; j < 8; j++)
    in[j].v = *(const int4*)&vb[(size_t)(b * SEQ + s0 + sd * 8 + j) * DIM + h * 64 + dd * 8];
#pragma unroll
  for (int i = 0; i < 8; i++)
#pragma unroll
    for (int j = 0; j < 8; j++) out[i].u[j] = in[j].u[i];
#pragma unroll
  for (int i = 0; i < 8; i++)
    *(int4*)&vT[((size_t)bh * 64 + dd * 8 + i) * SEQ + s0 + sd * 8] = out[i].v;
}

// ---------------- flash attention v2: bf16 in, QBLK=128, swizzled LDS ----------------
__global__ __launch_bounds__(256) void attn2_kernel(
    const ushort_t* __restrict__ qb, const ushort_t* __restrict__ kb,
    const ushort_t* __restrict__ vT, const float* __restrict__ mask,
    float* __restrict__ obuf) {
  __shared__ alignas(16) ushort_t Ks[64 * 64];
  __shared__ alignas(16) ushort_t Vs[64 * 64];   // Vs[d][key] (from vT)
  __shared__ alignas(16) ushort_t Ps[128 * 72];
  __shared__ float maskv[64];

  // XCD-aware decode: 512 blocks, 64 per XCD, contiguous (bh, qt) per XCD
  const int lin = blockIdx.x;
  const int logical = (lin & 7) * 64 + (lin >> 3);
  const int bh = logical >> 4;      // 0..31
  const int qt = logical & 15;      // 0..15
  const int b = bh >> 4, h = bh & 15;
  const size_t tokbase = (size_t)b * SEQ;
  const int q0 = qt * 128;

  const int tid = threadIdx.x;
  const int wv = tid >> 6, lane = tid & 63, l15 = lane & 15, hi = lane >> 4;

  // Q fragments in registers: rows q0 + wv*32 + rb*16 + l15
  short8 qf[2][2];
#pragma unroll
  for (int rb = 0; rb < 2; rb++)
#pragma unroll
    for (int ks = 0; ks < 2; ks++) {
      int row = q0 + wv * 32 + rb * 16 + l15;
      qf[rb][ks] = *(const short8*)&qb[(tokbase + row) * DIM + h * 64 + ks * 32 + hi * 8];
    }

  float mo[2][4], ls[2][4];
  f32x4 o[2][4];
#pragma unroll
  for (int rb = 0; rb < 2; rb++)
#pragma unroll
    for (int r = 0; r < 4; r++) { mo[rb][r] = -1e30f; ls[rb][r] = 0.f; }
#pragma unroll
  for (int rb = 0; rb < 2; rb++)
#pragma unroll
    for (int d = 0; d < 4; d++) { o[rb][d][0] = 0.f; o[rb][d][1] = 0.f; o[rb][d][2] = 0.f; o[rb][d][3] = 0.f; }

  for (int kt = 0; kt < 32; kt++) {
    const int k0 = kt * 64;
    __syncthreads();
    if (tid < 64) maskv[tid] = (1.0f - mask[tokbase + k0 + tid]) * -10000.0f;
#pragma unroll
    for (int it = 0; it < 2; it++) {
      int g = it * 256 + tid;
      int r = g >> 3, c = g & 7;
      int slot = (c ^ (r & 7)) * 8;
      *(int4*)&Ks[r * 64 + slot] = *(const int4*)&kb[(tokbase + k0 + r) * DIM + h * 64 + c * 8];
      *(int4*)&Vs[r * 64 + slot] = *(const int4*)&vT[((size_t)bh * 64 + r) * SEQ + k0 + c * 8];
    }
    __syncthreads();

    // S = Q K^T
    f32x4 s[2][4];
#pragma unroll
    for (int rb = 0; rb < 2; rb++)
#pragma unroll
      for (int cb = 0; cb < 4; cb++) { s[rb][cb][0] = 0.f; s[rb][cb][1] = 0.f; s[rb][cb][2] = 0.f; s[rb][cb][3] = 0.f; }
#pragma unroll
    for (int ks = 0; ks < 2; ks++) {
      short8 kf[4];
#pragma unroll
      for (int cb = 0; cb < 4; cb++) {
        int row = cb * 16 + l15;
        kf[cb] = *(const short8*)&Ks[row * 64 + (((ks * 4 + hi) ^ (row & 7))) * 8];
      }
#pragma unroll
      for (int rb = 0; rb < 2; rb++)
#pragma unroll
        for (int cb = 0; cb < 4; cb++)
          s[rb][cb] = __builtin_amdgcn_mfma_f32_16x16x32_bf16(qf[rb][ks], kf[cb], s[rb][cb], 0, 0, 0);
    }
#pragma unroll
    for (int rb = 0; rb < 2; rb++)
#pragma unroll
      for (int cb = 0; cb < 4; cb++) {
        float mk = maskv[cb * 16 + l15];
#pragma unroll
        for (int r = 0; r < 4; r++) s[rb][cb][r] = s[rb][cb][r] * 0.125f + mk;
      }

    // online softmax
    float al[2][4];
#pragma unroll
    for (int rb = 0; rb < 2; rb++)
#pragma unroll
      for (int r = 0; r < 4; r++) {
        float tm = fmaxf(fmaxf(s[rb][0][r], s[rb][1][r]), fmaxf(s[rb][2][r], s[rb][3][r]));
#pragma unroll
        for (int mm = 1; mm < 16; mm <<= 1) tm = fmaxf(tm, __shfl_xor(tm, mm));
        float mn = fmaxf(mo[rb][r], tm);
        al[rb][r] = __expf(mo[rb][r] - mn);
        mo[rb][r] = mn;
      }
    float rs[2][4];
#pragma unroll
    for (int rb = 0; rb < 2; rb++)
#pragma unroll
      for (int r = 0; r < 4; r++) rs[rb][r] = 0.f;
#pragma unroll
    for (int rb = 0; rb < 2; rb++)
#pragma unroll
      for (int cb = 0; cb < 4; cb++)
#pragma unroll
        for (int r = 0; r < 4; r++) {
          float pv = __expf(s[rb][cb][r] - mo[rb][r]);
          s[rb][cb][r] = pv;
          rs[rb][r] += pv;
        }
#pragma unroll
    for (int rb = 0; rb < 2; rb++)
#pragma unroll
      for (int r = 0; r < 4; r++) {
        float v = rs[rb][r];
#pragma unroll
        for (int mm = 1; mm < 16; mm <<= 1) v += __shfl_xor(v, mm);
        ls[rb][r] = ls[rb][r] * al[rb][r] + v;
#pragma unroll
        for (int d = 0; d < 4; d++) o[rb][d][r] *= al[rb][r];
      }
    // P -> LDS (per-wave rows, no barrier needed)
#pragma unroll
    for (int rb = 0; rb < 2; rb++)
#pragma unroll
      for (int cb = 0; cb < 4; cb++)
#pragma unroll
        for (int r = 0; r < 4; r++)
          Ps[(wv * 32 + rb * 16 + hi * 4 + r) * 72 + cb * 16 + l15] = f2bf(s[rb][cb][r]);
    // O += P V
#pragma unroll
    for (int ks = 0; ks < 2; ks++) {
      short8 pf[2];
#pragma unroll
      for (int rb = 0; rb < 2; rb++) {
        int row = wv * 32 + rb * 16 + l15;
        pf[rb] = *(const short8*)&Ps[row * 72 + ks * 32 + hi * 8];
      }
      short8 vf[4];
#pragma unroll
      for (int db = 0; db < 4; db++) {
        int row = db * 16 + l15;
        vf[db] = *(const short8*)&Vs[row * 64 + (((ks * 4 + hi) ^ (row & 7))) * 8];
      }
#pragma unroll
      for (int rb = 0; rb < 2; rb++)
#pragma unroll
        for (int db = 0; db < 4; db++)
          o[rb][db] = __builtin_amdgcn_mfma_f32_16x16x32_bf16(pf[rb], vf[db], o[rb][db], 0, 0, 0);
    }
  }

#pragma unroll
  for (int rb = 0; rb < 2; rb++)
#pragma unroll
    for (int r = 0; r < 4; r++) {
      float inv = 1.0f / ls[rb][r];
      size_t row = tokbase + q0 + wv * 32 + rb * 16 + hi * 4 + r;
#pragma unroll
      for (int db = 0; db < 4; db++)
        obuf[row * DIM + h * 64 + db * 16 + l15] = o[rb][db][r] * inv;
    }
}

// ---------------- launcher ----------------
extern "C" void kernel_launch(void* const* d_in, const int* in_sizes, int n_in,
                              void* d_out, int out_size, void* d_ws, size_t ws_size,
                              hipStream_t stream) {
  const float* x     = (const float*)d_in[0];
  const float* mask  = (const float*)d_in[1];
  const float* q_W   = (const float*)d_in[2];
  const float* q_b   = (const float*)d_in[3];
  const float* q_A   = (const float*)d_in[4];
  const float* q_B   = (const float*)d_in[5];
  const float* k_W   = (const float*)d_in[6];
  const float* k_b   = (const float*)d_in[7];
  const float* k_A   = (const float*)d_in[8];
  const float* k_B   = (const float*)d_in[9];
  const float* v_W   = (const float*)d_in[10];
  const float* v_b   = (const float*)d_in[11];
  const float* v_A   = (const float*)d_in[12];
  const float* v_B   = (const float*)d_in[13];
  const float* o_W   = (const float*)d_in[14];
  const float* o_b   = (const float*)d_in[15];
  const float* o_A   = (const float*)d_in[16];
  const float* o_B   = (const float*)d_in[17];
  float* out = (float*)d_out;

  char* ws = (char*)d_ws;
  const size_t MB = 1u << 20;
  unsigned* slots = (unsigned*)ws;                  // 6 amax slots
  float* t_q = (float*)(ws + 4096);                 // 4096x8 f32 each
  float* t_k = t_q + MROWS * 8;
  float* t_v = t_k + MROWS * 8;
  float* t_o = t_v + MROWS * 8;
  ushort_t* xc  = (ushort_t*)(ws + 1 * MB);         // 4096x1024 bf16 codes
  ushort_t* qWc = (ushort_t*)(ws + 9 * MB);
  ushort_t* kWc = (ushort_t*)(ws + 11 * MB);
  ushort_t* vWc = (ushort_t*)(ws + 13 * MB);
  ushort_t* oWc = (ushort_t*)(ws + 15 * MB);
  ushort_t* qbb = (ushort_t*)(ws + 17 * MB);        // q bf16 [4096][1024]
  ushort_t* kbb = (ushort_t*)(ws + 25 * MB);
  ushort_t* vbb = (ushort_t*)(ws + 33 * MB);
  ushort_t* vTb = (ushort_t*)(ws + 41 * MB);        // [32*64][2048]
  float*    abuf = (float*)(ws + 49 * MB);          // attn out f32
  ushort_t* ac  = (ushort_t*)(ws + 65 * MB);

  hipMemsetAsync(ws, 0, 64, stream);

  const int NX4 = (MROWS * DIM) / 4;
  const int NW4 = (DIM * DIM) / 4;

  amax_kernel<<<1024, 256, 0, stream>>>(x, NX4, slots + 0);
  amax4_kernel<<<dim3(64, 4), 256, 0, stream>>>(q_W, k_W, v_W, o_W, NW4, slots + 1);

  quant_kernel<<<1024, 256, 0, stream>>>(x, xc, NX4, slots + 0);
  quant4_kernel<<<dim3(128, 4), 256, 0, stream>>>(q_W, k_W, v_W, o_W,
                                                  qWc, kWc, vWc, oWc, NW4, slots + 1);

  lora_t_kernel<3><<<MROWS, 256, 0, stream>>>(x, q_A, k_A, v_A, t_q, t_k, t_v);

  ProjSet pq = { qWc, slots + 1, q_b, t_q, q_B, qbb };
  ProjSet pk = { kWc, slots + 2, k_b, t_k, k_B, kbb };
  ProjSet pv = { vWc, slots + 3, v_b, t_v, v_B, vbb };
  proj_qkv_kernel<<<dim3(DIM / 128, MROWS / 128, 3), 256, 0, stream>>>(xc, slots + 0, pq, pk, pv);

  vtrans_kernel<<<dim3(SEQ / 64, BSZ * NHEAD), 64, 0, stream>>>(vbb, vTb);

  attn2_kernel<<<512, 256, 0, stream>>>(qbb, kbb, vTb, mask, abuf);

  amax_kernel<<<1024, 256, 0, stream>>>(abuf, NX4, slots + 5);
  quant_kernel<<<1024, 256, 0, stream>>>(abuf, ac, NX4, slots + 5);
  lora_t_kernel<1><<<MROWS, 256, 0, stream>>>(abuf, o_A, nullptr, nullptr, t_o, nullptr, nullptr);

  proj_out_kernel<<<dim3(DIM / 64, MROWS / 128), 256, 0, stream>>>(
      ac, oWc, slots + 5, slots + 4, o_b, t_o, o_B, out);
}